// Round 3
// baseline (759.026 us; speedup 1.0000x reference)
//
#include <hip/hip_runtime.h>
#include <hip/hip_bf16.h>
#include <cstdint>

typedef __bf16 bf16;
typedef bf16 bf16x2 __attribute__((ext_vector_type(2)));
typedef bf16 bf16x4 __attribute__((ext_vector_type(4)));
typedef bf16 bf16x8 __attribute__((ext_vector_type(8)));
typedef float f32x4 __attribute__((ext_vector_type(4)));
typedef unsigned int uint32x2_t __attribute__((ext_vector_type(2)));
typedef unsigned int uint32x4_t __attribute__((ext_vector_type(4)));

#define MFMA16(a, b, c) __builtin_amdgcn_mfma_f32_16x16x32_bf16((a), (b), (c), 0, 0, 0)

// 0.125 * log2(e): folded into Q at the QKV-GEMM epilogue
#define QSCALE 0.18033688011112042f

// async global->LDS DMA, 16B/lane. LDS dest must be wave-uniform base + lane*16.
__device__ inline void async16(const bf16* g, bf16* l) {
  __builtin_amdgcn_global_load_lds(
      (const __attribute__((address_space(1))) void*)g,
      (__attribute__((address_space(3))) void*)l, 16, 0, 0);
}

// ------------------------------------------------------------------
// fused cast fp32 -> bf16 for all four inputs (one launch)
// float4-index ranges: x[0,2097152) Wq[..2359296) Wkv[..2490368) Wproj[..2752512)
// ------------------------------------------------------------------
__global__ void cast_all(const float* __restrict__ x, const float* __restrict__ wq,
                         const float* __restrict__ wkv, const float* __restrict__ wp,
                         bf16* __restrict__ xb, bf16* __restrict__ w1b,
                         bf16* __restrict__ wpb) {
  const int i = blockIdx.x * blockDim.x + threadIdx.x;
  const float4* src;
  bf16x4* dst;
  int idx;
  if (i < 2097152) {
    src = (const float4*)x; dst = (bf16x4*)xb; idx = i;
  } else if (i < 2359296) {
    src = (const float4*)wq; dst = (bf16x4*)w1b; idx = i - 2097152;
  } else if (i < 2490368) {
    src = (const float4*)wkv; dst = (bf16x4*)(w1b + 1048576); idx = i - 2359296;
  } else {
    src = (const float4*)wp; dst = (bf16x4*)wpb; idx = i - 2490368;
  }
  const float4 v = src[idx];
  bf16x4 o;
  o.x = (bf16)v.x; o.y = (bf16)v.y; o.z = (bf16)v.z; o.w = (bf16)v.w;
  dst[idx] = o;
}

// ------------------------------------------------------------------
// GEMM1: C[m,e] = sum_c x[m,c] * W1[e,c]   (M=8192, N=1536, K=1024)
// global_load_lds staging, xor-swizzled unpadded LDS (stride 64).
// Q outputs pre-scaled by QSCALE for the attention exp2 domain.
// ------------------------------------------------------------------
__global__ __launch_bounds__(256, 2)
void gemm_qkv(const bf16* __restrict__ A, const bf16* __restrict__ B,
              bf16* __restrict__ qb, bf16* __restrict__ kb, bf16* __restrict__ vb) {
  constexpr int K = 1024;
  __shared__ bf16 sA[128 * 64];
  __shared__ bf16 sB[128 * 64];
  const int tid = threadIdx.x;
  const int lane = tid & 63, wid = tid >> 6;
  const int col = lane & 15, quad = lane >> 4;
  const int wm = wid >> 1, wn = wid & 1;
  const int m0 = blockIdx.y * 128, n0 = blockIdx.x * 128;
  const int c7 = col & 7;

  f32x4 acc[4][4];
  const f32x4 z = {0.f, 0.f, 0.f, 0.f};
#pragma unroll
  for (int mi = 0; mi < 4; mi++)
#pragma unroll
    for (int ni = 0; ni < 4; ni++) acc[mi][ni] = z;

  for (int k0 = 0; k0 < K; k0 += 64) {
    __syncthreads();
#pragma unroll
    for (int c = 0; c < 4; ++c) {
      const int idx = c * 256 + tid;
      const int row = idx >> 3, kc = idx & 7;
      const int gkc = kc ^ (row & 7);
      async16(&A[(size_t)(m0 + row) * K + k0 + gkc * 8], &sA[idx * 8]);
      async16(&B[(size_t)(n0 + row) * K + k0 + gkc * 8], &sB[idx * 8]);
    }
    __syncthreads();  // vmcnt(0) drain: DMA complete
#pragma unroll
    for (int ks = 0; ks < 2; ++ks) {
      bf16x8 af[4], bfr[4];
#pragma unroll
      for (int i = 0; i < 4; i++)
        af[i] = *(const bf16x8*)&sA[(wm * 64 + i * 16 + col) * 64 +
                                    (((ks * 4 + quad) ^ c7) << 3)];
#pragma unroll
      for (int i = 0; i < 4; i++)
        bfr[i] = *(const bf16x8*)&sB[(wn * 64 + i * 16 + col) * 64 +
                                     (((ks * 4 + quad) ^ c7) << 3)];
#pragma unroll
      for (int mi = 0; mi < 4; mi++)
#pragma unroll
        for (int ni = 0; ni < 4; ni++)
          acc[mi][ni] = MFMA16(af[mi], bfr[ni], acc[mi][ni]);
    }
  }
#pragma unroll
  for (int mi = 0; mi < 4; mi++) {
#pragma unroll
    for (int ni = 0; ni < 4; ni++) {
      const int e = n0 + wn * 64 + ni * 16 + col;
#pragma unroll
      for (int r = 0; r < 4; r++) {
        const int m = m0 + wm * 64 + mi * 16 + quad * 4 + r;
        const int bb = m >> 11, t = m & 2047;
        if (e < 1024) {
          qb[(((size_t)bb * 16 + (e >> 6)) * 2048 + t) * 64 + (e & 63)] =
              (bf16)(acc[mi][ni][r] * QSCALE);
        } else if (e < 1280) {
          const int f = e - 1024;
          kb[(((size_t)bb * 4 + (f >> 6)) * 2048 + t) * 64 + (f & 63)] =
              (bf16)acc[mi][ni][r];
        } else {
          const int f = e - 1280;
          vb[(((size_t)bb * 4 + (f >> 6)) * 2048 + t) * 64 + (f & 63)] =
              (bf16)acc[mi][ni][r];
        }
      }
    }
  }
}

// ------------------------------------------------------------------
// GEMM2: out[m,e] = sum_c AO[m,c] * Wproj[e,c] + bias[e]  (fp32 out)
// ------------------------------------------------------------------
__global__ __launch_bounds__(256, 2)
void gemm_proj(const bf16* __restrict__ A, const bf16* __restrict__ B,
               const float* __restrict__ bias, float* __restrict__ out) {
  constexpr int K = 1024;
  __shared__ bf16 sA[128 * 64];
  __shared__ bf16 sB[128 * 64];
  const int tid = threadIdx.x;
  const int lane = tid & 63, wid = tid >> 6;
  const int col = lane & 15, quad = lane >> 4;
  const int wm = wid >> 1, wn = wid & 1;
  const int m0 = blockIdx.y * 128, n0 = blockIdx.x * 128;
  const int c7 = col & 7;

  f32x4 acc[4][4];
  const f32x4 z = {0.f, 0.f, 0.f, 0.f};
#pragma unroll
  for (int mi = 0; mi < 4; mi++)
#pragma unroll
    for (int ni = 0; ni < 4; ni++) acc[mi][ni] = z;

  for (int k0 = 0; k0 < K; k0 += 64) {
    __syncthreads();
#pragma unroll
    for (int c = 0; c < 4; ++c) {
      const int idx = c * 256 + tid;
      const int row = idx >> 3, kc = idx & 7;
      const int gkc = kc ^ (row & 7);
      async16(&A[(size_t)(m0 + row) * K + k0 + gkc * 8], &sA[idx * 8]);
      async16(&B[(size_t)(n0 + row) * K + k0 + gkc * 8], &sB[idx * 8]);
    }
    __syncthreads();
#pragma unroll
    for (int ks = 0; ks < 2; ++ks) {
      bf16x8 af[4], bfr[4];
#pragma unroll
      for (int i = 0; i < 4; i++)
        af[i] = *(const bf16x8*)&sA[(wm * 64 + i * 16 + col) * 64 +
                                    (((ks * 4 + quad) ^ c7) << 3)];
#pragma unroll
      for (int i = 0; i < 4; i++)
        bfr[i] = *(const bf16x8*)&sB[(wn * 64 + i * 16 + col) * 64 +
                                     (((ks * 4 + quad) ^ c7) << 3)];
#pragma unroll
      for (int mi = 0; mi < 4; mi++)
#pragma unroll
        for (int ni = 0; ni < 4; ni++)
          acc[mi][ni] = MFMA16(af[mi], bfr[ni], acc[mi][ni]);
    }
  }
#pragma unroll
  for (int mi = 0; mi < 4; mi++) {
#pragma unroll
    for (int ni = 0; ni < 4; ni++) {
      const int e = n0 + wn * 64 + ni * 16 + col;
      const float be = bias[e];
#pragma unroll
      for (int r = 0; r < 4; r++) {
        const int m = m0 + wm * 64 + mi * 16 + quad * 4 + r;
        out[(size_t)m * 1024 + e] = acc[mi][ni][r] + be;
      }
    }
  }
}

// ------------------------------------------------------------------
// Flash attention, ALiBi bias, fixed-max softmax, transposed dataflow.
// KV-SPLIT: blockIdx.z in {0,1} selects kv range [z*1024, z*1024+1024).
// Fixed-max softmax -> partials combine exactly: O=(O0+O1)/(s0+s1).
// Grid (8,64,2)=1024 blocks = 4 blocks/CU = 4 waves/SIMD; per-pipe totals
// identical to the 2-block/CU version (same waves x chunks product).
// 64 q-rows/wave. K staged by global_load_lds (pre-swizzled source);
// V double-buffered via regs. P stays IN REGISTERS (cvt_pk +
// permlane32/16_swap repack). ONE __syncthreads per chunk.
// Row sums via all-ones MFMA B-operand. Q pre-scaled (exp2 domain).
// ------------------------------------------------------------------
__global__ __launch_bounds__(256, 4)
void attn_alibi(const bf16* __restrict__ qb, const bf16* __restrict__ kb,
                const bf16* __restrict__ vb, float* __restrict__ po,
                float* __restrict__ ps) {
  __shared__ bf16 sK[2][64 * 64];   // [buf][kv][d], xor-swizzled stride 64 (DMA-filled)
  __shared__ bf16 sVt[2][64 * 72];  // [buf][d][kv], stride 72, kv-block xor-swizzle
  const int tid = threadIdx.x;
  const int lane = tid & 63, wid = tid >> 6;
  const int col = lane & 15, quad = lane >> 4;
  const int c7 = col & 7;
  const int bh = blockIdx.y;
  const int b = bh >> 4, h = bh & 15, kvh = h & 3;
  const int kvsplit = blockIdx.z;
  const int kbeg = kvsplit << 10, kend = kbeg + 1024;
  const int qbase = __builtin_amdgcn_readfirstlane(blockIdx.x * 256 + wid * 64);

  const bf16* qptr = qb + ((size_t)(b * 16 + h) * 2048 + qbase) * 64;
  const bf16* kptr = kb + ((size_t)(b * 4 + kvh) * 2048) * 64;
  const bf16* vptr = vb + ((size_t)(b * 4 + kvh) * 2048) * 64;

  // Q resident as B-operand frags: B[n=q (col)][k=d]
  bf16x8 bq[4][2];
#pragma unroll
  for (int ni = 0; ni < 4; ni++)
#pragma unroll
    for (int ks = 0; ks < 2; ks++)
      bq[ni][ks] = *(const bf16x8*)&qptr[(ni * 16 + col) * 64 + ks * 32 + quad * 8];

  // all-ones B-frag for MFMA row sums
  bf16x8 bones;
#pragma unroll
  for (int j = 0; j < 8; j++) bones[j] = (bf16)1.0f;

  f32x4 O[4][4];  // O[q-tile][d-tile], C-layout rows=q
  f32x4 Osum[4];  // row sums of P per q-tile
  const f32x4 z = {0.f, 0.f, 0.f, 0.f};
#pragma unroll
  for (int mi = 0; mi < 4; mi++) {
    Osum[mi] = z;
#pragma unroll
    for (int nd = 0; nd < 4; nd++) O[mi][nd] = z;
  }

  const float cb = exp2f(-0.5f * (float)(h + 1)) * QSCALE;  // bias slope, exp2 domain
  const int qoff = quad * 4 - col;

  // K DMA coords: two issues per thread, rows rowA and rowA+32, source pre-swizzled
  const int rowA = tid >> 3, kc = tid & 7;
  const int kxA = (kc ^ (rowA & 7)) << 3;  // (rowA+32)&7 == rowA&7
  // V staging coords: row pair (2*(tid>>3), +1)
  const int rv = rowA * 2;
  const int blkv = rv >> 3, rlv = rv & 7;

  // prologue: K chunk kbeg -> sK[0] via DMA; V chunk kbeg -> regs
  async16(&kptr[(size_t)(kbeg + rowA) * 64 + kxA], &sK[0][tid * 8]);
  async16(&kptr[(size_t)(kbeg + rowA + 32) * 64 + kxA], &sK[0][(256 + tid) * 8]);
  bf16x8 vr0 = *(const bf16x8*)&vptr[(size_t)(kbeg + rv) * 64 + kc * 8];
  bf16x8 vr1 = *(const bf16x8*)&vptr[(size_t)(kbeg + rv + 1) * 64 + kc * 8];

  int bufi = 0;
  for (int c0 = kbeg; c0 < kend; c0 += 64, bufi ^= 1) {
    bf16* skw = sK[bufi];
    bf16* svw = sVt[bufi];
    // commit prefetched V regs to current buffer (transposed, swizzled)
#pragma unroll
    for (int j = 0; j < 8; j++) {
      bf16x2 pr;
      pr.x = vr0[j];
      pr.y = vr1[j];
      *(bf16x2*)&svw[(kc * 8 + j) * 72 + ((blkv ^ kc) << 3) + rlv] = pr;
    }
    __syncthreads();  // single barrier: drains K DMA (vmcnt) + V writes visible

    // issue next chunk's K DMA + V loads — whole compute phase covers latency
    {
      const int cn = (c0 + 64 < kend) ? c0 + 64 : kbeg;
      bf16* skn = sK[bufi ^ 1];
      async16(&kptr[(size_t)(cn + rowA) * 64 + kxA], &skn[tid * 8]);
      async16(&kptr[(size_t)(cn + rowA + 32) * 64 + kxA], &skn[(256 + tid) * 8]);
      vr0 = *(const bf16x8*)&vptr[(size_t)(cn + rv) * 64 + kc * 8];
      vr1 = *(const bf16x8*)&vptr[(size_t)(cn + rv + 1) * 64 + kc * 8];
    }

    // S^T = K Q^T : rows=kv, cols=q  (Q pre-scaled: S is in exp2 domain)
    // ks=0 writes fresh accumulators from the constant zero quad (no v_mov init)
    f32x4 S[4][4];
    {
      bf16x8 ak[4];
#pragma unroll
      for (int mi = 0; mi < 4; mi++)
        ak[mi] = *(const bf16x8*)&skw[(mi * 16 + col) * 64 + ((quad ^ c7) << 3)];
      __builtin_amdgcn_s_setprio(1);
#pragma unroll
      for (int mi = 0; mi < 4; mi++)
#pragma unroll
        for (int ni = 0; ni < 4; ni++)
          S[mi][ni] = MFMA16(ak[mi], bq[ni][0], z);
      __builtin_amdgcn_s_setprio(0);
#pragma unroll
      for (int mi = 0; mi < 4; mi++)
        ak[mi] = *(const bf16x8*)&skw[(mi * 16 + col) * 64 + (((4 + quad) ^ c7) << 3)];
      __builtin_amdgcn_s_setprio(1);
#pragma unroll
      for (int mi = 0; mi < 4; mi++)
#pragma unroll
        for (int ni = 0; ni < 4; ni++)
          S[mi][ni] = MFMA16(ak[mi], bq[ni][1], S[mi][ni]);
      __builtin_amdgcn_s_setprio(0);
    }

    // bias + exp2 (fixed max M=0), then repack S^T quads -> PV A-frags in-register:
    // lane(quad,col) holds P[q=col][kv=16mi+4quad+r]; A-frag wants kv=32ks+8quad+j.
    // pack r-pairs to bf16x2 words, then permlane32_swap (E/O tiles) +
    // permlane16_swap (lo/hi word split) -> no LDS round-trip.
    bf16x8 ap[4][2];
#pragma unroll
    for (int ni = 0; ni < 4; ni++) {
#pragma unroll
      for (int ks = 0; ks < 2; ks++) {
        unsigned plo[2], phi[2];
#pragma unroll
        for (int t = 0; t < 2; t++) {
          const int mi = ks * 2 + t;
          const int U = c0 + mi * 16 - qbase - ni * 16;  // wave-uniform
          f32x4 p;
          if (U <= -15) {
            const float bb = cb * (float)(U + qoff);
#pragma unroll
            for (int r = 0; r < 4; r++)
              p[r] = __builtin_amdgcn_exp2f(S[mi][ni][r] + (bb + cb * (float)r));
          } else if (U >= 16) {
#pragma unroll
            for (int r = 0; r < 4; r++)
              p[r] = __builtin_amdgcn_exp2f(S[mi][ni][r]);
          } else {
            const float relf = (float)(U + qoff);
#pragma unroll
            for (int r = 0; r < 4; r++) {
              const float rr = relf + (float)r;
              const float bb = (rr <= 0.f) ? cb * rr : 0.f;
              p[r] = __builtin_amdgcn_exp2f(S[mi][ni][r] + bb);
            }
          }
          bf16x2 lo, hi;
          lo.x = (bf16)p[0]; lo.y = (bf16)p[1];
          hi.x = (bf16)p[2]; hi.y = (bf16)p[3];
          plo[t] = __builtin_bit_cast(unsigned, lo);
          phi[t] = __builtin_bit_cast(unsigned, hi);
        }
        // [A,B,C,D] per quad of even tile; [A',B',C',D'] odd tile
        uint32x2_t rl = __builtin_amdgcn_permlane32_swap(plo[0], plo[1], false, false);
        uint32x2_t rh = __builtin_amdgcn_permlane32_swap(phi[0], phi[1], false, false);
        // rl = {[A,B,A',B'], [C,D,C',D']} (lo words); rh same for hi words
        uint32x2_t w02 = __builtin_amdgcn_permlane16_swap(rl.x, rl.y, false, false);
        uint32x2_t w13 = __builtin_amdgcn_permlane16_swap(rh.x, rh.y, false, false);
        // w02 = {[A,C,A',C'], [B,D,B',D']} lo ; w13 same hi
        uint32x4_t W;
        W.x = w02.x; W.y = w13.x; W.z = w02.y; W.w = w13.y;
        ap[ni][ks] = __builtin_bit_cast(bf16x8, W);
      }
    }

    // O += P V ; Osum += P · 1   (ap in registers — no LDS dependency)
#pragma unroll
    for (int ks = 0; ks < 2; ks++) {
      bf16x8 bv[4];
#pragma unroll
      for (int nd = 0; nd < 4; nd++) {
        const int d = nd * 16 + col;
        bv[nd] = *(const bf16x8*)&svw[d * 72 + (((ks * 4 + quad) ^ (d >> 3)) << 3)];
      }
      __builtin_amdgcn_s_setprio(1);
#pragma unroll
      for (int mi = 0; mi < 4; mi++) {
#pragma unroll
        for (int nd = 0; nd < 4; nd++)
          O[mi][nd] = MFMA16(ap[mi][ks], bv[nd], O[mi][nd]);
        Osum[mi] = MFMA16(ap[mi][ks], bones, Osum[mi]);
      }
      __builtin_amdgcn_s_setprio(0);
    }
  }

  // epilogue: write f32 partials; lane holds row sum in Osum[mi][r]
  float* pob = po + ((size_t)(kvsplit * 64 + bh) * 2048) * 64;
  float* psb = ps + (size_t)(kvsplit * 64 + bh) * 2048;
#pragma unroll
  for (int mi = 0; mi < 4; mi++) {
#pragma unroll
    for (int r = 0; r < 4; r++) {
      const int t = qbase + mi * 16 + quad * 4 + r;
      if (col == 0) psb[t] = Osum[mi][r];
#pragma unroll
      for (int nd = 0; nd < 4; nd++) {
        pob[(size_t)t * 64 + nd * 16 + col] = O[mi][nd][r];
      }
    }
  }
}

// ------------------------------------------------------------------
// combine: O = (O0 + O1) / (s0 + s1), write bf16 [b][t][h*64+d]
// po: [2][64][2048][64] f32 ; ps: [2][64][2048] f32
// ------------------------------------------------------------------
__global__ void combine_o(const float* __restrict__ po, const float* __restrict__ ps,
                          bf16* __restrict__ ob) {
  const int i = blockIdx.x * 256 + threadIdx.x;  // 2097152 threads, 4 elems each
  const int dq = i & 15;
  const int t = (i >> 4) & 2047;
  const int bh = i >> 15;
  const size_t base0 = ((size_t)bh * 2048 + t) * 64 + dq * 4;
  const size_t base1 = ((size_t)(64 + bh) * 2048 + t) * 64 + dq * 4;
  const float4 a = *(const float4*)&po[base0];
  const float4 c = *(const float4*)&po[base1];
  const float inv = 1.0f / (ps[bh * 2048 + t] + ps[(64 + bh) * 2048 + t]);
  bf16x4 o;
  o.x = (bf16)((a.x + c.x) * inv);
  o.y = (bf16)((a.y + c.y) * inv);
  o.z = (bf16)((a.z + c.z) * inv);
  o.w = (bf16)((a.w + c.w) * inv);
  const int b = bh >> 4, h = bh & 15;
  *(bf16x4*)&ob[((size_t)b * 2048 + t) * 1024 + h * 64 + dq * 4] = o;
}

// ------------------------------------------------------------------
extern "C" void kernel_launch(void* const* d_in, const int* in_sizes, int n_in,
                              void* d_out, int out_size, void* d_ws, size_t ws_size,
                              hipStream_t stream) {
  const float* x     = (const float*)d_in[0];
  const float* Wq    = (const float*)d_in[1];
  const float* Wkv   = (const float*)d_in[2];
  const float* Wproj = (const float*)d_in[3];
  const float* bproj = (const float*)d_in[4];
  float* out = (float*)d_out;

  bf16* xb  = (bf16*)d_ws;            // 8192*1024
  bf16* w1b = xb  + 8388608;          // 1536*1024
  bf16* wpb = w1b + 1572864;          // 1024*1024
  bf16* qb  = wpb + 1048576;          // [4,16,2048,64]
  bf16* kb  = qb  + 8388608;          // [4,4,2048,64]
  bf16* vb  = kb  + 2097152;          // [4,4,2048,64]
  bf16* aob = vb  + 2097152;          // [4,2048,1024]
  float* po = (float*)(aob + 8388608); // [2,64,2048,64] f32 partial O (64MB)
  float* ps = po + 16777216;           // [2,64,2048] f32 partial sums (1MB)

  cast_all<<<10752, 256, 0, stream>>>(x, Wq, Wkv, Wproj, xb, w1b, wpb);
  gemm_qkv<<<dim3(12, 64), 256, 0, stream>>>(xb, w1b, qb, kb, vb);
  attn_alibi<<<dim3(8, 64, 2), 256, 0, stream>>>(qb, kb, vb, po, ps);
  combine_o<<<8192, 256, 0, stream>>>(po, ps, aob);
  gemm_proj<<<dim3(8, 64), 256, 0, stream>>>(aob, wpb, bproj, out);
}

// Round 4
// 262.387 us; speedup vs baseline: 2.8928x; 2.8928x over previous
//
#include <hip/hip_runtime.h>
#include <hip/hip_bf16.h>
#include <cstdint>

typedef __bf16 bf16;
typedef bf16 bf16x2 __attribute__((ext_vector_type(2)));
typedef bf16 bf16x4 __attribute__((ext_vector_type(4)));
typedef bf16 bf16x8 __attribute__((ext_vector_type(8)));
typedef float f32x4 __attribute__((ext_vector_type(4)));
typedef unsigned int uint32x2_t __attribute__((ext_vector_type(2)));
typedef unsigned int uint32x4_t __attribute__((ext_vector_type(4)));

#define MFMA16(a, b, c) __builtin_amdgcn_mfma_f32_16x16x32_bf16((a), (b), (c), 0, 0, 0)

// 0.125 * log2(e): folded into Q at the QKV-GEMM epilogue
#define QSCALE 0.18033688011112042f

// async global->LDS DMA, 16B/lane. LDS dest must be wave-uniform base + lane*16.
__device__ inline void async16(const bf16* g, bf16* l) {
  __builtin_amdgcn_global_load_lds(
      (const __attribute__((address_space(1))) void*)g,
      (__attribute__((address_space(3))) void*)l, 16, 0, 0);
}

// ------------------------------------------------------------------
// fused cast fp32 -> bf16 for all four inputs (one launch)
// float4-index ranges: x[0,2097152) Wq[..2359296) Wkv[..2490368) Wproj[..2752512)
// ------------------------------------------------------------------
__global__ void cast_all(const float* __restrict__ x, const float* __restrict__ wq,
                         const float* __restrict__ wkv, const float* __restrict__ wp,
                         bf16* __restrict__ xb, bf16* __restrict__ w1b,
                         bf16* __restrict__ wpb) {
  const int i = blockIdx.x * blockDim.x + threadIdx.x;
  const float4* src;
  bf16x4* dst;
  int idx;
  if (i < 2097152) {
    src = (const float4*)x; dst = (bf16x4*)xb; idx = i;
  } else if (i < 2359296) {
    src = (const float4*)wq; dst = (bf16x4*)w1b; idx = i - 2097152;
  } else if (i < 2490368) {
    src = (const float4*)wkv; dst = (bf16x4*)(w1b + 1048576); idx = i - 2359296;
  } else {
    src = (const float4*)wp; dst = (bf16x4*)wpb; idx = i - 2490368;
  }
  const float4 v = src[idx];
  bf16x4 o;
  o.x = (bf16)v.x; o.y = (bf16)v.y; o.z = (bf16)v.z; o.w = (bf16)v.w;
  dst[idx] = o;
}

// ------------------------------------------------------------------
// GEMM1: C[m,e] = sum_c x[m,c] * W1[e,c]   (M=8192, N=1536, K=1024)
// global_load_lds staging, xor-swizzled unpadded LDS (stride 64).
// Q outputs pre-scaled by QSCALE for the attention exp2 domain.
// ------------------------------------------------------------------
__global__ __launch_bounds__(256, 2)
void gemm_qkv(const bf16* __restrict__ A, const bf16* __restrict__ B,
              bf16* __restrict__ qb, bf16* __restrict__ kb, bf16* __restrict__ vb) {
  constexpr int K = 1024;
  __shared__ bf16 sA[128 * 64];
  __shared__ bf16 sB[128 * 64];
  const int tid = threadIdx.x;
  const int lane = tid & 63, wid = tid >> 6;
  const int col = lane & 15, quad = lane >> 4;
  const int wm = wid >> 1, wn = wid & 1;
  const int m0 = blockIdx.y * 128, n0 = blockIdx.x * 128;
  const int c7 = col & 7;

  f32x4 acc[4][4];
  const f32x4 z = {0.f, 0.f, 0.f, 0.f};
#pragma unroll
  for (int mi = 0; mi < 4; mi++)
#pragma unroll
    for (int ni = 0; ni < 4; ni++) acc[mi][ni] = z;

  for (int k0 = 0; k0 < K; k0 += 64) {
    __syncthreads();
#pragma unroll
    for (int c = 0; c < 4; ++c) {
      const int idx = c * 256 + tid;
      const int row = idx >> 3, kc = idx & 7;
      const int gkc = kc ^ (row & 7);
      async16(&A[(size_t)(m0 + row) * K + k0 + gkc * 8], &sA[idx * 8]);
      async16(&B[(size_t)(n0 + row) * K + k0 + gkc * 8], &sB[idx * 8]);
    }
    __syncthreads();  // vmcnt(0) drain: DMA complete
#pragma unroll
    for (int ks = 0; ks < 2; ++ks) {
      bf16x8 af[4], bfr[4];
#pragma unroll
      for (int i = 0; i < 4; i++)
        af[i] = *(const bf16x8*)&sA[(wm * 64 + i * 16 + col) * 64 +
                                    (((ks * 4 + quad) ^ c7) << 3)];
#pragma unroll
      for (int i = 0; i < 4; i++)
        bfr[i] = *(const bf16x8*)&sB[(wn * 64 + i * 16 + col) * 64 +
                                     (((ks * 4 + quad) ^ c7) << 3)];
#pragma unroll
      for (int mi = 0; mi < 4; mi++)
#pragma unroll
        for (int ni = 0; ni < 4; ni++)
          acc[mi][ni] = MFMA16(af[mi], bfr[ni], acc[mi][ni]);
    }
  }
#pragma unroll
  for (int mi = 0; mi < 4; mi++) {
#pragma unroll
    for (int ni = 0; ni < 4; ni++) {
      const int e = n0 + wn * 64 + ni * 16 + col;
#pragma unroll
      for (int r = 0; r < 4; r++) {
        const int m = m0 + wm * 64 + mi * 16 + quad * 4 + r;
        const int bb = m >> 11, t = m & 2047;
        if (e < 1024) {
          qb[(((size_t)bb * 16 + (e >> 6)) * 2048 + t) * 64 + (e & 63)] =
              (bf16)(acc[mi][ni][r] * QSCALE);
        } else if (e < 1280) {
          const int f = e - 1024;
          kb[(((size_t)bb * 4 + (f >> 6)) * 2048 + t) * 64 + (f & 63)] =
              (bf16)acc[mi][ni][r];
        } else {
          const int f = e - 1280;
          vb[(((size_t)bb * 4 + (f >> 6)) * 2048 + t) * 64 + (f & 63)] =
              (bf16)acc[mi][ni][r];
        }
      }
    }
  }
}

// ------------------------------------------------------------------
// GEMM2: out[m,e] = sum_c AO[m,c] * Wproj[e,c] + bias[e]  (fp32 out)
// ------------------------------------------------------------------
__global__ __launch_bounds__(256, 2)
void gemm_proj(const bf16* __restrict__ A, const bf16* __restrict__ B,
               const float* __restrict__ bias, float* __restrict__ out) {
  constexpr int K = 1024;
  __shared__ bf16 sA[128 * 64];
  __shared__ bf16 sB[128 * 64];
  const int tid = threadIdx.x;
  const int lane = tid & 63, wid = tid >> 6;
  const int col = lane & 15, quad = lane >> 4;
  const int wm = wid >> 1, wn = wid & 1;
  const int m0 = blockIdx.y * 128, n0 = blockIdx.x * 128;
  const int c7 = col & 7;

  f32x4 acc[4][4];
  const f32x4 z = {0.f, 0.f, 0.f, 0.f};
#pragma unroll
  for (int mi = 0; mi < 4; mi++)
#pragma unroll
    for (int ni = 0; ni < 4; ni++) acc[mi][ni] = z;

  for (int k0 = 0; k0 < K; k0 += 64) {
    __syncthreads();
#pragma unroll
    for (int c = 0; c < 4; ++c) {
      const int idx = c * 256 + tid;
      const int row = idx >> 3, kc = idx & 7;
      const int gkc = kc ^ (row & 7);
      async16(&A[(size_t)(m0 + row) * K + k0 + gkc * 8], &sA[idx * 8]);
      async16(&B[(size_t)(n0 + row) * K + k0 + gkc * 8], &sB[idx * 8]);
    }
    __syncthreads();
#pragma unroll
    for (int ks = 0; ks < 2; ++ks) {
      bf16x8 af[4], bfr[4];
#pragma unroll
      for (int i = 0; i < 4; i++)
        af[i] = *(const bf16x8*)&sA[(wm * 64 + i * 16 + col) * 64 +
                                    (((ks * 4 + quad) ^ c7) << 3)];
#pragma unroll
      for (int i = 0; i < 4; i++)
        bfr[i] = *(const bf16x8*)&sB[(wn * 64 + i * 16 + col) * 64 +
                                     (((ks * 4 + quad) ^ c7) << 3)];
#pragma unroll
      for (int mi = 0; mi < 4; mi++)
#pragma unroll
        for (int ni = 0; ni < 4; ni++)
          acc[mi][ni] = MFMA16(af[mi], bfr[ni], acc[mi][ni]);
    }
  }
#pragma unroll
  for (int mi = 0; mi < 4; mi++) {
#pragma unroll
    for (int ni = 0; ni < 4; ni++) {
      const int e = n0 + wn * 64 + ni * 16 + col;
      const float be = bias[e];
#pragma unroll
      for (int r = 0; r < 4; r++) {
        const int m = m0 + wm * 64 + mi * 16 + quad * 4 + r;
        out[(size_t)m * 1024 + e] = acc[mi][ni][r] + be;
      }
    }
  }
}

// ------------------------------------------------------------------
// Flash attention, ALiBi bias, fixed-max softmax, transposed dataflow.
// KV-SPLIT: blockIdx.z in {0,1} selects kv range [z*1024, z*1024+1024).
// Fixed-max softmax -> partials combine exactly: O=(O0+O1)/(s0+s1).
// Grid (8,64,2)=1024 blocks. launch_bounds stays (256,2): the round-1
// body compiles to ~120 VGPR which is ALREADY in the 4-waves/SIMD tier
// (<=128); LDS 34KB allows 4 blocks/CU. (256,4) forced the allocator
// into a 64-VGPR spill catastrophe (1.49 GB scratch traffic) - do NOT
// cap VGPRs; occupancy comes from grid size + natural allocation.
// 64 q-rows/wave. K staged by global_load_lds (pre-swizzled source);
// V double-buffered via regs. P stays IN REGISTERS (cvt_pk +
// permlane32/16_swap repack). ONE __syncthreads per chunk.
// Row sums via all-ones MFMA B-operand. Q pre-scaled (exp2 domain).
// ------------------------------------------------------------------
__global__ __launch_bounds__(256, 2)
void attn_alibi(const bf16* __restrict__ qb, const bf16* __restrict__ kb,
                const bf16* __restrict__ vb, float* __restrict__ po,
                float* __restrict__ ps) {
  __shared__ bf16 sK[2][64 * 64];   // [buf][kv][d], xor-swizzled stride 64 (DMA-filled)
  __shared__ bf16 sVt[2][64 * 72];  // [buf][d][kv], stride 72, kv-block xor-swizzle
  const int tid = threadIdx.x;
  const int lane = tid & 63, wid = tid >> 6;
  const int col = lane & 15, quad = lane >> 4;
  const int c7 = col & 7;
  const int bh = blockIdx.y;
  const int b = bh >> 4, h = bh & 15, kvh = h & 3;
  const int kvsplit = blockIdx.z;
  const int kbeg = kvsplit << 10, kend = kbeg + 1024;
  const int qbase = __builtin_amdgcn_readfirstlane(blockIdx.x * 256 + wid * 64);

  const bf16* qptr = qb + ((size_t)(b * 16 + h) * 2048 + qbase) * 64;
  const bf16* kptr = kb + ((size_t)(b * 4 + kvh) * 2048) * 64;
  const bf16* vptr = vb + ((size_t)(b * 4 + kvh) * 2048) * 64;

  // Q resident as B-operand frags: B[n=q (col)][k=d]
  bf16x8 bq[4][2];
#pragma unroll
  for (int ni = 0; ni < 4; ni++)
#pragma unroll
    for (int ks = 0; ks < 2; ks++)
      bq[ni][ks] = *(const bf16x8*)&qptr[(ni * 16 + col) * 64 + ks * 32 + quad * 8];

  // all-ones B-frag for MFMA row sums
  bf16x8 bones;
#pragma unroll
  for (int j = 0; j < 8; j++) bones[j] = (bf16)1.0f;

  f32x4 O[4][4];  // O[q-tile][d-tile], C-layout rows=q
  f32x4 Osum[4];  // row sums of P per q-tile
  const f32x4 z = {0.f, 0.f, 0.f, 0.f};
#pragma unroll
  for (int mi = 0; mi < 4; mi++) {
    Osum[mi] = z;
#pragma unroll
    for (int nd = 0; nd < 4; nd++) O[mi][nd] = z;
  }

  const float cb = exp2f(-0.5f * (float)(h + 1)) * QSCALE;  // bias slope, exp2 domain
  const int qoff = quad * 4 - col;

  // K DMA coords: two issues per thread, rows rowA and rowA+32, source pre-swizzled
  const int rowA = tid >> 3, kc = tid & 7;
  const int kxA = (kc ^ (rowA & 7)) << 3;  // (rowA+32)&7 == rowA&7
  // V staging coords: row pair (2*(tid>>3), +1)
  const int rv = rowA * 2;
  const int blkv = rv >> 3, rlv = rv & 7;

  // prologue: K chunk kbeg -> sK[0] via DMA; V chunk kbeg -> regs
  async16(&kptr[(size_t)(kbeg + rowA) * 64 + kxA], &sK[0][tid * 8]);
  async16(&kptr[(size_t)(kbeg + rowA + 32) * 64 + kxA], &sK[0][(256 + tid) * 8]);
  bf16x8 vr0 = *(const bf16x8*)&vptr[(size_t)(kbeg + rv) * 64 + kc * 8];
  bf16x8 vr1 = *(const bf16x8*)&vptr[(size_t)(kbeg + rv + 1) * 64 + kc * 8];

  int bufi = 0;
  for (int c0 = kbeg; c0 < kend; c0 += 64, bufi ^= 1) {
    bf16* skw = sK[bufi];
    bf16* svw = sVt[bufi];
    // commit prefetched V regs to current buffer (transposed, swizzled)
#pragma unroll
    for (int j = 0; j < 8; j++) {
      bf16x2 pr;
      pr.x = vr0[j];
      pr.y = vr1[j];
      *(bf16x2*)&svw[(kc * 8 + j) * 72 + ((blkv ^ kc) << 3) + rlv] = pr;
    }
    __syncthreads();  // single barrier: drains K DMA (vmcnt) + V writes visible

    // issue next chunk's K DMA + V loads — whole compute phase covers latency
    {
      const int cn = (c0 + 64 < kend) ? c0 + 64 : kbeg;
      bf16* skn = sK[bufi ^ 1];
      async16(&kptr[(size_t)(cn + rowA) * 64 + kxA], &skn[tid * 8]);
      async16(&kptr[(size_t)(cn + rowA + 32) * 64 + kxA], &skn[(256 + tid) * 8]);
      vr0 = *(const bf16x8*)&vptr[(size_t)(cn + rv) * 64 + kc * 8];
      vr1 = *(const bf16x8*)&vptr[(size_t)(cn + rv + 1) * 64 + kc * 8];
    }

    // S^T = K Q^T : rows=kv, cols=q  (Q pre-scaled: S is in exp2 domain)
    // ks=0 writes fresh accumulators from the constant zero quad (no v_mov init)
    f32x4 S[4][4];
    {
      bf16x8 ak[4];
#pragma unroll
      for (int mi = 0; mi < 4; mi++)
        ak[mi] = *(const bf16x8*)&skw[(mi * 16 + col) * 64 + ((quad ^ c7) << 3)];
      __builtin_amdgcn_s_setprio(1);
#pragma unroll
      for (int mi = 0; mi < 4; mi++)
#pragma unroll
        for (int ni = 0; ni < 4; ni++)
          S[mi][ni] = MFMA16(ak[mi], bq[ni][0], z);
      __builtin_amdgcn_s_setprio(0);
#pragma unroll
      for (int mi = 0; mi < 4; mi++)
        ak[mi] = *(const bf16x8*)&skw[(mi * 16 + col) * 64 + (((4 + quad) ^ c7) << 3)];
      __builtin_amdgcn_s_setprio(1);
#pragma unroll
      for (int mi = 0; mi < 4; mi++)
#pragma unroll
        for (int ni = 0; ni < 4; ni++)
          S[mi][ni] = MFMA16(ak[mi], bq[ni][1], S[mi][ni]);
      __builtin_amdgcn_s_setprio(0);
    }

    // bias + exp2 (fixed max M=0), then repack S^T quads -> PV A-frags in-register:
    // lane(quad,col) holds P[q=col][kv=16mi+4quad+r]; A-frag wants kv=32ks+8quad+j.
    // pack r-pairs to bf16x2 words, then permlane32_swap (E/O tiles) +
    // permlane16_swap (lo/hi word split) -> no LDS round-trip.
    bf16x8 ap[4][2];
#pragma unroll
    for (int ni = 0; ni < 4; ni++) {
#pragma unroll
      for (int ks = 0; ks < 2; ks++) {
        unsigned plo[2], phi[2];
#pragma unroll
        for (int t = 0; t < 2; t++) {
          const int mi = ks * 2 + t;
          const int U = c0 + mi * 16 - qbase - ni * 16;  // wave-uniform
          f32x4 p;
          if (U <= -15) {
            const float bb = cb * (float)(U + qoff);
#pragma unroll
            for (int r = 0; r < 4; r++)
              p[r] = __builtin_amdgcn_exp2f(S[mi][ni][r] + (bb + cb * (float)r));
          } else if (U >= 16) {
#pragma unroll
            for (int r = 0; r < 4; r++)
              p[r] = __builtin_amdgcn_exp2f(S[mi][ni][r]);
          } else {
            const float relf = (float)(U + qoff);
#pragma unroll
            for (int r = 0; r < 4; r++) {
              const float rr = relf + (float)r;
              const float bb = (rr <= 0.f) ? cb * rr : 0.f;
              p[r] = __builtin_amdgcn_exp2f(S[mi][ni][r] + bb);
            }
          }
          bf16x2 lo, hi;
          lo.x = (bf16)p[0]; lo.y = (bf16)p[1];
          hi.x = (bf16)p[2]; hi.y = (bf16)p[3];
          plo[t] = __builtin_bit_cast(unsigned, lo);
          phi[t] = __builtin_bit_cast(unsigned, hi);
        }
        // [A,B,C,D] per quad of even tile; [A',B',C',D'] odd tile
        uint32x2_t rl = __builtin_amdgcn_permlane32_swap(plo[0], plo[1], false, false);
        uint32x2_t rh = __builtin_amdgcn_permlane32_swap(phi[0], phi[1], false, false);
        // rl = {[A,B,A',B'], [C,D,C',D']} (lo words); rh same for hi words
        uint32x2_t w02 = __builtin_amdgcn_permlane16_swap(rl.x, rl.y, false, false);
        uint32x2_t w13 = __builtin_amdgcn_permlane16_swap(rh.x, rh.y, false, false);
        // w02 = {[A,C,A',C'], [B,D,B',D']} lo ; w13 same hi
        uint32x4_t W;
        W.x = w02.x; W.y = w13.x; W.z = w02.y; W.w = w13.y;
        ap[ni][ks] = __builtin_bit_cast(bf16x8, W);
      }
    }

    // O += P V ; Osum += P · 1   (ap in registers — no LDS dependency)
#pragma unroll
    for (int ks = 0; ks < 2; ks++) {
      bf16x8 bv[4];
#pragma unroll
      for (int nd = 0; nd < 4; nd++) {
        const int d = nd * 16 + col;
        bv[nd] = *(const bf16x8*)&svw[d * 72 + (((ks * 4 + quad) ^ (d >> 3)) << 3)];
      }
      __builtin_amdgcn_s_setprio(1);
#pragma unroll
      for (int mi = 0; mi < 4; mi++) {
#pragma unroll
        for (int nd = 0; nd < 4; nd++)
          O[mi][nd] = MFMA16(ap[mi][ks], bv[nd], O[mi][nd]);
        Osum[mi] = MFMA16(ap[mi][ks], bones, Osum[mi]);
      }
      __builtin_amdgcn_s_setprio(0);
    }
  }

  // epilogue: write f32 partials; lane holds row sum in Osum[mi][r]
  float* pob = po + ((size_t)(kvsplit * 64 + bh) * 2048) * 64;
  float* psb = ps + (size_t)(kvsplit * 64 + bh) * 2048;
#pragma unroll
  for (int mi = 0; mi < 4; mi++) {
#pragma unroll
    for (int r = 0; r < 4; r++) {
      const int t = qbase + mi * 16 + quad * 4 + r;
      if (col == 0) psb[t] = Osum[mi][r];
#pragma unroll
      for (int nd = 0; nd < 4; nd++) {
        pob[(size_t)t * 64 + nd * 16 + col] = O[mi][nd][r];
      }
    }
  }
}

// ------------------------------------------------------------------
// combine: O = (O0 + O1) / (s0 + s1), write bf16 [b][t][h*64+d]
// po: [2][64][2048][64] f32 ; ps: [2][64][2048] f32
// ------------------------------------------------------------------
__global__ void combine_o(const float* __restrict__ po, const float* __restrict__ ps,
                          bf16* __restrict__ ob) {
  const int i = blockIdx.x * 256 + threadIdx.x;  // 2097152 threads, 4 elems each
  const int dq = i & 15;
  const int t = (i >> 4) & 2047;
  const int bh = i >> 15;
  const size_t base0 = ((size_t)bh * 2048 + t) * 64 + dq * 4;
  const size_t base1 = ((size_t)(64 + bh) * 2048 + t) * 64 + dq * 4;
  const float4 a = *(const float4*)&po[base0];
  const float4 c = *(const float4*)&po[base1];
  const float inv = 1.0f / (ps[bh * 2048 + t] + ps[(64 + bh) * 2048 + t]);
  bf16x4 o;
  o.x = (bf16)((a.x + c.x) * inv);
  o.y = (bf16)((a.y + c.y) * inv);
  o.z = (bf16)((a.z + c.z) * inv);
  o.w = (bf16)((a.w + c.w) * inv);
  const int b = bh >> 4, h = bh & 15;
  *(bf16x4*)&ob[((size_t)b * 2048 + t) * 1024 + h * 64 + dq * 4] = o;
}

// ------------------------------------------------------------------
extern "C" void kernel_launch(void* const* d_in, const int* in_sizes, int n_in,
                              void* d_out, int out_size, void* d_ws, size_t ws_size,
                              hipStream_t stream) {
  const float* x     = (const float*)d_in[0];
  const float* Wq    = (const float*)d_in[1];
  const float* Wkv   = (const float*)d_in[2];
  const float* Wproj = (const float*)d_in[3];
  const float* bproj = (const float*)d_in[4];
  float* out = (float*)d_out;

  bf16* xb  = (bf16*)d_ws;            // 8192*1024
  bf16* w1b = xb  + 8388608;          // 1536*1024
  bf16* wpb = w1b + 1572864;          // 1024*1024
  bf16* qb  = wpb + 1048576;          // [4,16,2048,64]
  bf16* kb  = qb  + 8388608;          // [4,4,2048,64]
  bf16* vb  = kb  + 2097152;          // [4,4,2048,64]
  bf16* aob = vb  + 2097152;          // [4,2048,1024]
  float* po = (float*)(aob + 8388608); // [2,64,2048,64] f32 partial O (64MB)
  float* ps = po + 16777216;           // [2,64,2048] f32 partial sums (1MB)

  cast_all<<<10752, 256, 0, stream>>>(x, Wq, Wkv, Wproj, xb, w1b, wpb);
  gemm_qkv<<<dim3(12, 64), 256, 0, stream>>>(xb, w1b, qb, kb, vb);
  attn_alibi<<<dim3(8, 64, 2), 256, 0, stream>>>(qb, kb, vb, po, ps);
  combine_o<<<8192, 256, 0, stream>>>(po, ps, aob);
  gemm_proj<<<dim3(8, 64), 256, 0, stream>>>(aob, wpb, bproj, out);
}

// Round 5
// 239.710 us; speedup vs baseline: 3.1664x; 1.0946x over previous
//
#include <hip/hip_runtime.h>
#include <hip/hip_bf16.h>
#include <cstdint>

typedef __bf16 bf16;
typedef bf16 bf16x2 __attribute__((ext_vector_type(2)));
typedef bf16 bf16x4 __attribute__((ext_vector_type(4)));
typedef bf16 bf16x8 __attribute__((ext_vector_type(8)));
typedef float f32x4 __attribute__((ext_vector_type(4)));
typedef unsigned int uint32x2_t __attribute__((ext_vector_type(2)));
typedef unsigned int uint32x4_t __attribute__((ext_vector_type(4)));

#define MFMA16(a, b, c) __builtin_amdgcn_mfma_f32_16x16x32_bf16((a), (b), (c), 0, 0, 0)

// 0.125 * log2(e): folded into Q at the QKV-GEMM epilogue
#define QSCALE 0.18033688011112042f

// async global->LDS DMA, 16B/lane. LDS dest must be wave-uniform base + lane*16.
__device__ inline void async16(const bf16* g, bf16* l) {
  __builtin_amdgcn_global_load_lds(
      (const __attribute__((address_space(1))) void*)g,
      (__attribute__((address_space(3))) void*)l, 16, 0, 0);
}

// ------------------------------------------------------------------
// fused cast fp32 -> bf16 for all four inputs (one launch)
// float4-index ranges: x[0,2097152) Wq[..2359296) Wkv[..2490368) Wproj[..2752512)
// ------------------------------------------------------------------
__global__ void cast_all(const float* __restrict__ x, const float* __restrict__ wq,
                         const float* __restrict__ wkv, const float* __restrict__ wp,
                         bf16* __restrict__ xb, bf16* __restrict__ w1b,
                         bf16* __restrict__ wpb) {
  const int i = blockIdx.x * blockDim.x + threadIdx.x;
  const float4* src;
  bf16x4* dst;
  int idx;
  if (i < 2097152) {
    src = (const float4*)x; dst = (bf16x4*)xb; idx = i;
  } else if (i < 2359296) {
    src = (const float4*)wq; dst = (bf16x4*)w1b; idx = i - 2097152;
  } else if (i < 2490368) {
    src = (const float4*)wkv; dst = (bf16x4*)(w1b + 1048576); idx = i - 2359296;
  } else {
    src = (const float4*)wp; dst = (bf16x4*)wpb; idx = i - 2490368;
  }
  const float4 v = src[idx];
  bf16x4 o;
  o.x = (bf16)v.x; o.y = (bf16)v.y; o.z = (bf16)v.z; o.w = (bf16)v.w;
  dst[idx] = o;
}

// ------------------------------------------------------------------
// GEMM1: C[m,e] = sum_c x[m,c] * W1[e,c]   (M=8192, N=1536, K=1024)
// ------------------------------------------------------------------
__global__ __launch_bounds__(256, 2)
void gemm_qkv(const bf16* __restrict__ A, const bf16* __restrict__ B,
              bf16* __restrict__ qb, bf16* __restrict__ kb, bf16* __restrict__ vb) {
  constexpr int K = 1024;
  __shared__ bf16 sA[128 * 64];
  __shared__ bf16 sB[128 * 64];
  const int tid = threadIdx.x;
  const int lane = tid & 63, wid = tid >> 6;
  const int col = lane & 15, quad = lane >> 4;
  const int wm = wid >> 1, wn = wid & 1;
  const int m0 = blockIdx.y * 128, n0 = blockIdx.x * 128;
  const int c7 = col & 7;

  f32x4 acc[4][4];
  const f32x4 z = {0.f, 0.f, 0.f, 0.f};
#pragma unroll
  for (int mi = 0; mi < 4; mi++)
#pragma unroll
    for (int ni = 0; ni < 4; ni++) acc[mi][ni] = z;

  for (int k0 = 0; k0 < K; k0 += 64) {
    __syncthreads();
#pragma unroll
    for (int c = 0; c < 4; ++c) {
      const int idx = c * 256 + tid;
      const int row = idx >> 3, kc = idx & 7;
      const int gkc = kc ^ (row & 7);
      async16(&A[(size_t)(m0 + row) * K + k0 + gkc * 8], &sA[idx * 8]);
      async16(&B[(size_t)(n0 + row) * K + k0 + gkc * 8], &sB[idx * 8]);
    }
    __syncthreads();  // vmcnt(0) drain: DMA complete
#pragma unroll
    for (int ks = 0; ks < 2; ++ks) {
      bf16x8 af[4], bfr[4];
#pragma unroll
      for (int i = 0; i < 4; i++)
        af[i] = *(const bf16x8*)&sA[(wm * 64 + i * 16 + col) * 64 +
                                    (((ks * 4 + quad) ^ c7) << 3)];
#pragma unroll
      for (int i = 0; i < 4; i++)
        bfr[i] = *(const bf16x8*)&sB[(wn * 64 + i * 16 + col) * 64 +
                                     (((ks * 4 + quad) ^ c7) << 3)];
#pragma unroll
      for (int mi = 0; mi < 4; mi++)
#pragma unroll
        for (int ni = 0; ni < 4; ni++)
          acc[mi][ni] = MFMA16(af[mi], bfr[ni], acc[mi][ni]);
    }
  }
#pragma unroll
  for (int mi = 0; mi < 4; mi++) {
#pragma unroll
    for (int ni = 0; ni < 4; ni++) {
      const int e = n0 + wn * 64 + ni * 16 + col;
#pragma unroll
      for (int r = 0; r < 4; r++) {
        const int m = m0 + wm * 64 + mi * 16 + quad * 4 + r;
        const int bb = m >> 11, t = m & 2047;
        if (e < 1024) {
          qb[(((size_t)bb * 16 + (e >> 6)) * 2048 + t) * 64 + (e & 63)] =
              (bf16)(acc[mi][ni][r] * QSCALE);
        } else if (e < 1280) {
          const int f = e - 1024;
          kb[(((size_t)bb * 4 + (f >> 6)) * 2048 + t) * 64 + (f & 63)] =
              (bf16)acc[mi][ni][r];
        } else {
          const int f = e - 1280;
          vb[(((size_t)bb * 4 + (f >> 6)) * 2048 + t) * 64 + (f & 63)] =
              (bf16)acc[mi][ni][r];
        }
      }
    }
  }
}

// ------------------------------------------------------------------
// GEMM2: out[m,e] = sum_c AO[m,c] * Wproj[e,c] + bias[e]  (fp32 out)
// ------------------------------------------------------------------
__global__ __launch_bounds__(256, 2)
void gemm_proj(const bf16* __restrict__ A, const bf16* __restrict__ B,
               const float* __restrict__ bias, float* __restrict__ out) {
  constexpr int K = 1024;
  __shared__ bf16 sA[128 * 64];
  __shared__ bf16 sB[128 * 64];
  const int tid = threadIdx.x;
  const int lane = tid & 63, wid = tid >> 6;
  const int col = lane & 15, quad = lane >> 4;
  const int wm = wid >> 1, wn = wid & 1;
  const int m0 = blockIdx.y * 128, n0 = blockIdx.x * 128;
  const int c7 = col & 7;

  f32x4 acc[4][4];
  const f32x4 z = {0.f, 0.f, 0.f, 0.f};
#pragma unroll
  for (int mi = 0; mi < 4; mi++)
#pragma unroll
    for (int ni = 0; ni < 4; ni++) acc[mi][ni] = z;

  for (int k0 = 0; k0 < K; k0 += 64) {
    __syncthreads();
#pragma unroll
    for (int c = 0; c < 4; ++c) {
      const int idx = c * 256 + tid;
      const int row = idx >> 3, kc = idx & 7;
      const int gkc = kc ^ (row & 7);
      async16(&A[(size_t)(m0 + row) * K + k0 + gkc * 8], &sA[idx * 8]);
      async16(&B[(size_t)(n0 + row) * K + k0 + gkc * 8], &sB[idx * 8]);
    }
    __syncthreads();
#pragma unroll
    for (int ks = 0; ks < 2; ++ks) {
      bf16x8 af[4], bfr[4];
#pragma unroll
      for (int i = 0; i < 4; i++)
        af[i] = *(const bf16x8*)&sA[(wm * 64 + i * 16 + col) * 64 +
                                    (((ks * 4 + quad) ^ c7) << 3)];
#pragma unroll
      for (int i = 0; i < 4; i++)
        bfr[i] = *(const bf16x8*)&sB[(wn * 64 + i * 16 + col) * 64 +
                                     (((ks * 4 + quad) ^ c7) << 3)];
#pragma unroll
      for (int mi = 0; mi < 4; mi++)
#pragma unroll
        for (int ni = 0; ni < 4; ni++)
          acc[mi][ni] = MFMA16(af[mi], bfr[ni], acc[mi][ni]);
    }
  }
#pragma unroll
  for (int mi = 0; mi < 4; mi++) {
#pragma unroll
    for (int ni = 0; ni < 4; ni++) {
      const int e = n0 + wn * 64 + ni * 16 + col;
      const float be = bias[e];
#pragma unroll
      for (int r = 0; r < 4; r++) {
        const int m = m0 + wm * 64 + mi * 16 + quad * 4 + r;
        out[(size_t)m * 1024 + e] = acc[mi][ni][r] + be;
      }
    }
  }
}

// ==================================================================
// Flash attention, ALiBi bias, fixed-max softmax, transposed dataflow.
// T15 INTRA-WAVE PIPELINE: PV lags one chunk. Per iteration:
//   QK(c) MFMA -> PV(c-1) ks0 MFMA -> softmax(c) strip A (VALU, overlaps
//   the in-flight MFMAs) -> QK already done -> PV(c-1) ks1 -> softmax B.
// ap[ni][ks] is overwritten IN-PLACE right after its lagged PV consumed
// it (no extra register state); S is processed as two 2x4 strips (the
// pack pairing {mi0,1}->ap[*][0], {mi2,3}->ap[*][1]) so peak pressure
// stays ~unchanged. V is TRIPLE-buffered (PV reads one chunk behind
// staging; barrier(i+1) separates read(i) from overwrite(i+2)).
// K stays double-buffered via global_load_lds (pre-swizzled source).
// Occupancy note: total arch+acc regs ~250/wave => 2 waves/SIMD tier;
// occupancy lever is exhausted (r2/r4 evidence), so overlap must come
// from within the wave - that is this structure.
// ==================================================================
#define COMMIT_V(svc_)                                                      \
  _Pragma("unroll")                                                         \
  for (int j = 0; j < 8; j++) {                                             \
    bf16x2 pr; pr.x = vr0[j]; pr.y = vr1[j];                                \
    *(bf16x2*)&(svc_)[(kc * 8 + j) * 72 + ((blkv ^ kc) << 3) + rlv] = pr;   \
  }

#define QK_STRIP(Sx_, mb_)                                                  \
  {                                                                         \
    bf16x8 ak0[2], ak1[2];                                                  \
    _Pragma("unroll")                                                       \
    for (int t = 0; t < 2; t++) {                                           \
      ak0[t] = *(const bf16x8*)&skw[(((mb_) + t) * 16 + col) * 64 +         \
                                    ((quad ^ c7) << 3)];                    \
      ak1[t] = *(const bf16x8*)&skw[(((mb_) + t) * 16 + col) * 64 +         \
                                    (((4 + quad) ^ c7) << 3)];              \
    }                                                                       \
    __builtin_amdgcn_s_setprio(1);                                          \
    _Pragma("unroll")                                                       \
    for (int t = 0; t < 2; t++)                                             \
      _Pragma("unroll")                                                     \
      for (int ni = 0; ni < 4; ni++)                                        \
        Sx_[t][ni] = MFMA16(ak0[t], bq[ni][0], z);                          \
    _Pragma("unroll")                                                       \
    for (int t = 0; t < 2; t++)                                             \
      _Pragma("unroll")                                                     \
      for (int ni = 0; ni < 4; ni++)                                        \
        Sx_[t][ni] = MFMA16(ak1[t], bq[ni][1], Sx_[t][ni]);                 \
    __builtin_amdgcn_s_setprio(0);                                          \
  }

#define PV_KS(kspv_, svp_)                                                  \
  {                                                                         \
    bf16x8 bv[4];                                                           \
    _Pragma("unroll")                                                       \
    for (int nd = 0; nd < 4; nd++) {                                        \
      const int d = nd * 16 + col;                                          \
      bv[nd] = *(const bf16x8*)&(svp_)[d * 72 +                             \
                   ((((kspv_) * 4 + quad) ^ (d >> 3)) << 3)];               \
    }                                                                       \
    __builtin_amdgcn_s_setprio(1);                                          \
    _Pragma("unroll")                                                       \
    for (int mi = 0; mi < 4; mi++) {                                        \
      _Pragma("unroll")                                                     \
      for (int nd = 0; nd < 4; nd++)                                        \
        O[mi][nd] = MFMA16(ap[mi][kspv_], bv[nd], O[mi][nd]);               \
      Osum[mi] = MFMA16(ap[mi][kspv_], bones, Osum[mi]);                    \
    }                                                                       \
    __builtin_amdgcn_s_setprio(0);                                          \
  }

#define SM_STRIP(Sx_, mb_, kspv_)                                           \
  _Pragma("unroll")                                                         \
  for (int ni = 0; ni < 4; ni++) {                                          \
    unsigned plo[2], phi[2];                                                \
    _Pragma("unroll")                                                       \
    for (int t = 0; t < 2; t++) {                                           \
      const int U = c0 + ((mb_) + t) * 16 - qbase - ni * 16;                \
      f32x4 p;                                                              \
      if (U <= -15) {                                                       \
        const float bb = cb * (float)(U + qoff);                            \
        _Pragma("unroll")                                                   \
        for (int r = 0; r < 4; r++)                                         \
          p[r] = __builtin_amdgcn_exp2f(Sx_[t][ni][r] + (bb + cb * (float)r)); \
      } else if (U >= 16) {                                                 \
        _Pragma("unroll")                                                   \
        for (int r = 0; r < 4; r++)                                         \
          p[r] = __builtin_amdgcn_exp2f(Sx_[t][ni][r]);                     \
      } else {                                                              \
        const float relf = (float)(U + qoff);                               \
        _Pragma("unroll")                                                   \
        for (int r = 0; r < 4; r++) {                                       \
          const float rr = relf + (float)r;                                 \
          const float bb = (rr <= 0.f) ? cb * rr : 0.f;                     \
          p[r] = __builtin_amdgcn_exp2f(Sx_[t][ni][r] + bb);                \
        }                                                                   \
      }                                                                     \
      bf16x2 lo, hi;                                                        \
      lo.x = (bf16)p[0]; lo.y = (bf16)p[1];                                 \
      hi.x = (bf16)p[2]; hi.y = (bf16)p[3];                                 \
      plo[t] = __builtin_bit_cast(unsigned, lo);                            \
      phi[t] = __builtin_bit_cast(unsigned, hi);                            \
    }                                                                       \
    uint32x2_t rl = __builtin_amdgcn_permlane32_swap(plo[0], plo[1], false, false); \
    uint32x2_t rh = __builtin_amdgcn_permlane32_swap(phi[0], phi[1], false, false); \
    uint32x2_t w02 = __builtin_amdgcn_permlane16_swap(rl.x, rl.y, false, false);    \
    uint32x2_t w13 = __builtin_amdgcn_permlane16_swap(rh.x, rh.y, false, false);    \
    uint32x4_t W;                                                           \
    W.x = w02.x; W.y = w13.x; W.z = w02.y; W.w = w13.y;                     \
    ap[ni][kspv_] = __builtin_bit_cast(bf16x8, W);                          \
  }

__global__ __launch_bounds__(256, 2)
void attn_alibi(const bf16* __restrict__ qb, const bf16* __restrict__ kb,
                const bf16* __restrict__ vb, bf16* __restrict__ ob) {
  __shared__ bf16 sK[2][64 * 64];   // [buf][kv][d], xor-swizzled stride 64 (DMA)
  __shared__ bf16 sVt[3][64 * 72];  // [buf][d][kv], stride 72, kv-block xor-swizzle
  const int tid = threadIdx.x;
  const int lane = tid & 63, wid = tid >> 6;
  const int col = lane & 15, quad = lane >> 4;
  const int c7 = col & 7;
  const int bh = blockIdx.y;
  const int b = bh >> 4, h = bh & 15, kvh = h & 3;
  const int qbase = __builtin_amdgcn_readfirstlane(blockIdx.x * 256 + wid * 64);

  const bf16* qptr = qb + ((size_t)(b * 16 + h) * 2048 + qbase) * 64;
  const bf16* kptr = kb + ((size_t)(b * 4 + kvh) * 2048) * 64;
  const bf16* vptr = vb + ((size_t)(b * 4 + kvh) * 2048) * 64;

  // Q resident as B-operand frags: B[n=q (col)][k=d]
  bf16x8 bq[4][2];
#pragma unroll
  for (int ni = 0; ni < 4; ni++)
#pragma unroll
    for (int ks = 0; ks < 2; ks++)
      bq[ni][ks] = *(const bf16x8*)&qptr[(ni * 16 + col) * 64 + ks * 32 + quad * 8];

  // all-ones B-frag for MFMA row sums
  bf16x8 bones;
#pragma unroll
  for (int j = 0; j < 8; j++) bones[j] = (bf16)1.0f;

  f32x4 O[4][4];
  f32x4 Osum[4];
  const f32x4 z = {0.f, 0.f, 0.f, 0.f};
#pragma unroll
  for (int mi = 0; mi < 4; mi++) {
    Osum[mi] = z;
#pragma unroll
    for (int nd = 0; nd < 4; nd++) O[mi][nd] = z;
  }

  const float cb = exp2f(-0.5f * (float)(h + 1)) * QSCALE;
  const int qoff = quad * 4 - col;

  // staging coords
  const int rowA = tid >> 3, kc = tid & 7;
  const int kxA = (kc ^ (rowA & 7)) << 3;
  const int rv = rowA * 2;
  const int blkv = rv >> 3, rlv = rv & 7;

  // prologue: K(0) -> sK[0] via DMA; V(0) -> regs
  async16(&kptr[(size_t)rowA * 64 + kxA], &sK[0][tid * 8]);
  async16(&kptr[(size_t)(rowA + 32) * 64 + kxA], &sK[0][(256 + tid) * 8]);
  bf16x8 vr0 = *(const bf16x8*)&vptr[(size_t)rv * 64 + kc * 8];
  bf16x8 vr1 = *(const bf16x8*)&vptr[(size_t)(rv + 1) * 64 + kc * 8];

  bf16x8 ap[4][2];  // persistent across iterations (lag-1 PV operand)

  // ---- peeled iteration i=0 (c0=0): QK+softmax only, no PV ----
  {
    const int c0 = 0;
    COMMIT_V(sVt[0]);
    __syncthreads();  // drains K(0) DMA, V(0) visible
    // issue chunk 1
    async16(&kptr[(size_t)(64 + rowA) * 64 + kxA], &sK[1][tid * 8]);
    async16(&kptr[(size_t)(64 + rowA + 32) * 64 + kxA], &sK[1][(256 + tid) * 8]);
    vr0 = *(const bf16x8*)&vptr[(size_t)(64 + rv) * 64 + kc * 8];
    vr1 = *(const bf16x8*)&vptr[(size_t)(64 + rv + 1) * 64 + kc * 8];

    const bf16* skw = sK[0];
    f32x4 Sa[2][4], Sb[2][4];
    QK_STRIP(Sa, 0);
    SM_STRIP(Sa, 0, 0);
    QK_STRIP(Sb, 2);
    SM_STRIP(Sb, 2, 1);
  }

  // ---- main loop: i = 1..31 ----
  int bufi = 1, ivc = 1, ivp = 0;
  for (int c0 = 64; c0 < 2048; c0 += 64) {
    const bf16* skw = sK[bufi];
    const bf16* svp = sVt[ivp];
    COMMIT_V(sVt[ivc]);
    __syncthreads();  // drains K(c0) DMA; V(c0) visible; V(c0-2) free

    {  // issue chunk c0+64 (wrap on last iter: dummy, proven benign)
      const int cn = (c0 + 64 < 2048) ? c0 + 64 : 0;
      bf16* skn = sK[bufi ^ 1];
      async16(&kptr[(size_t)(cn + rowA) * 64 + kxA], &skn[tid * 8]);
      async16(&kptr[(size_t)(cn + rowA + 32) * 64 + kxA], &skn[(256 + tid) * 8]);
      vr0 = *(const bf16x8*)&vptr[(size_t)(cn + rv) * 64 + kc * 8];
      vr1 = *(const bf16x8*)&vptr[(size_t)(cn + rv + 1) * 64 + kc * 8];
    }

    f32x4 Sa[2][4], Sb[2][4];
    // QK(c0) strip A, then lagged PV(c0-64) ks0 — both MFMA, independent;
    // softmax A (VALU) runs under the PV MFMA tail, rewrites ap[*][0] in place.
    QK_STRIP(Sa, 0);
    PV_KS(0, svp);
    SM_STRIP(Sa, 0, 0);
    QK_STRIP(Sb, 2);
    PV_KS(1, svp);
    SM_STRIP(Sb, 2, 1);

    bufi ^= 1;
    ivp = ivc;
    ivc = (ivc == 2) ? 0 : ivc + 1;
  }

  // ---- epilogue: lagged PV for the last chunk (c0=1984, V in sVt[ivp]) ----
  {
    const bf16* svp = sVt[ivp];
    PV_KS(0, svp);
    PV_KS(1, svp);
  }

  // normalize + store
#pragma unroll
  for (int mi = 0; mi < 4; mi++) {
#pragma unroll
    for (int r = 0; r < 4; r++) {
      const float inv = 1.0f / Osum[mi][r];
      const int t = qbase + mi * 16 + quad * 4 + r;
#pragma unroll
      for (int nd = 0; nd < 4; nd++) {
        ob[((size_t)b * 2048 + t) * 1024 + h * 64 + nd * 16 + col] =
            (bf16)(O[mi][nd][r] * inv);
      }
    }
  }
}

// ------------------------------------------------------------------
extern "C" void kernel_launch(void* const* d_in, const int* in_sizes, int n_in,
                              void* d_out, int out_size, void* d_ws, size_t ws_size,
                              hipStream_t stream) {
  const float* x     = (const float*)d_in[0];
  const float* Wq    = (const float*)d_in[1];
  const float* Wkv   = (const float*)d_in[2];
  const float* Wproj = (const float*)d_in[3];
  const float* bproj = (const float*)d_in[4];
  float* out = (float*)d_out;

  bf16* xb  = (bf16*)d_ws;            // 8192*1024
  bf16* w1b = xb  + 8388608;          // 1536*1024
  bf16* wpb = w1b + 1572864;          // 1024*1024
  bf16* qb  = wpb + 1048576;          // [4,16,2048,64]
  bf16* kb  = qb  + 8388608;          // [4,4,2048,64]
  bf16* vb  = kb  + 2097152;          // [4,4,2048,64]
  bf16* aob = vb  + 2097152;          // [4,2048,1024]

  cast_all<<<10752, 256, 0, stream>>>(x, Wq, Wkv, Wproj, xb, w1b, wpb);
  gemm_qkv<<<dim3(12, 64), 256, 0, stream>>>(xb, w1b, qb, kb, vb);
  attn_alibi<<<dim3(8, 64), 256, 0, stream>>>(qb, kb, vb, aob);
  gemm_proj<<<dim3(8, 64), 256, 0, stream>>>(aob, wpb, bproj, out);
}